// Round 7
// baseline (2381.997 us; speedup 1.0000x reference)
//
#include <hip/hip_runtime.h>
#include <hip/hip_bf16.h>

// CharRNN: 2-layer LSTM LM + softmax CE on MI355X (gfx950).
// Round 7: batched (branch-free) sentinel polling in the dataflow recurrence;
// B-register double-buffered MFMA pipelines + branchless online-lse in the
// CE and input-projection GEMMs.
// dims: V=8000, B=64, T=128, H=512.

#define V_SIZE 8000
#define B_SIZE 64
#define T_SIZE 128
#define H_SIZE 512
#define NROW   (B_SIZE * T_SIZE)     // 8192
#define NG     (4 * H_SIZE)          // 2048 gate columns
#define HB     (H_SIZE * B_SIZE)     // one h time-slice (bf16 elems)
#define RBLK   128                   // recurrence grid
#define RTH    256                   // recurrence block size
#define SENT   0x7FFF7FFFu

typedef __attribute__((ext_vector_type(8))) short bf16x8;
typedef __attribute__((ext_vector_type(8))) unsigned short u16x8;
typedef __attribute__((ext_vector_type(4))) float f32x4;

// ---------- bf16 helpers (raw ushort storage) ----------
__device__ __forceinline__ float bf2f(unsigned short u) {
  union { unsigned int i; float f; } x; x.i = ((unsigned int)u) << 16; return x.f;
}
__device__ __forceinline__ unsigned short f2bf(float f) {
  union { float f; unsigned int i; } x; x.f = f;
  unsigned int r = x.i + 0x7fffu + ((x.i >> 16) & 1u);
  return (unsigned short)(r >> 16);
}
__device__ __forceinline__ float sigf(float v) { return 1.f / (1.f + __expf(-v)); }
__device__ __forceinline__ float tanhf_fast(float v) {
  return 1.f - 2.f / (__expf(2.f * v) + 1.f);
}

// agent-scope (MALL-coherent) 16B A-fragment load as 2x u64
__device__ __forceinline__ bf16x8 aload16(const unsigned short* p) {
  unsigned long long lo = __hip_atomic_load((const unsigned long long*)p,
                                            __ATOMIC_RELAXED, __HIP_MEMORY_SCOPE_AGENT);
  unsigned long long hi = __hip_atomic_load((const unsigned long long*)(p + 4),
                                            __ATOMIC_RELAXED, __HIP_MEMORY_SCOPE_AGENT);
  union { unsigned long long v[2]; bf16x8 b; } u;
  u.v[0] = lo; u.v[1] = hi;
  return u.b;
}
__device__ __forceinline__ unsigned has_sent(bf16x8 v) {
  union { bf16x8 b; unsigned u[4]; } x; x.b = v;
  return (unsigned)((x.u[0] == SENT) | (x.u[1] == SENT) |
                    (x.u[2] == SENT) | (x.u[3] == SENT));
}

// ---------------- fill ----------------
__global__ void fill_k(unsigned* __restrict__ p, unsigned v, int n) {
  int i = blockIdx.x * 256 + threadIdx.x;
  if (i < n) p[i] = v;
}

// ---------------- embedding gather -> bf16 x [8192 rows=t*64+b][512] ----------------
__global__ __launch_bounds__(256) void xgather_k(const int* __restrict__ ids,
                                                 const float* __restrict__ emb,
                                                 unsigned short* __restrict__ xb) {
  int g = blockIdx.x * 256 + threadIdx.x;   // 8192 rows x 64 chunks of 8
  int r = g >> 6, c = g & 63;
  int t = r >> 6, b = r & 63;
  int id = ids[(size_t)b * T_SIZE + t];
  const float4* s4 = reinterpret_cast<const float4*>(emb + (size_t)id * H_SIZE + c * 8);
  float4 v0 = s4[0], v1 = s4[1];
  u16x8 o;
  o[0] = f2bf(v0.x); o[1] = f2bf(v0.y); o[2] = f2bf(v0.z); o[3] = f2bf(v0.w);
  o[4] = f2bf(v1.x); o[5] = f2bf(v1.y); o[6] = f2bf(v1.z); o[7] = f2bf(v1.w);
  *reinterpret_cast<u16x8*>(xb + (size_t)r * H_SIZE + c * 8) = o;
}

// ---------------- f32 [K][N] -> bf16 [N][K] transpose (64x64 tiles) ----------------
__global__ __launch_bounds__(256) void trans_k(const float* __restrict__ src,
                                               unsigned short* __restrict__ dst,
                                               int src_ld, int n_tiles) {
  __shared__ float tile[64][65];
  const int tid = threadIdx.x;
  const int kt = blockIdx.x / n_tiles, nt = blockIdx.x % n_tiles;
#pragma unroll
  for (int q = 0; q < 16; ++q) {
    int f = tid + 256 * q;
    int r = f >> 6, c = f & 63;
    tile[r][c] = src[(size_t)(kt * 64 + r) * src_ld + nt * 64 + c];
  }
  __syncthreads();
#pragma unroll
  for (int q = 0; q < 2; ++q) {
    int u = tid + 256 * q;
    int n = u >> 3, kg = u & 7;
    u16x8 o;
#pragma unroll
    for (int e = 0; e < 8; ++e) o[e] = f2bf(tile[kg * 8 + e][n]);
    *reinterpret_cast<u16x8*>(dst + (size_t)(nt * 64 + n) * 512 + kt * 64 + kg * 8) = o;
  }
}

// load 8 B-fragments (one K-half) for column vc from a [N][512] bf16 matrix
__device__ __forceinline__ void loadB8(bf16x8* p, const unsigned short* Wb,
                                       int vc, int kh, int kof) {
#pragma unroll
  for (int ks = 0; ks < 8; ++ks)
    p[ks] = *reinterpret_cast<const bf16x8*>(
        Wb + (size_t)vc * 512 + (kh * 8 + ks) * 32 + kof);
}

// ---------------- G1 = x @ W1x + b1 (MFMA, B-dbuf), bf16 out [t][b][2048] ----------------
__global__ __launch_bounds__(256) void gemm1mm_k(const unsigned short* __restrict__ xb,
                                                 const unsigned short* __restrict__ W1b,
                                                 const float* __restrict__ b1,
                                                 unsigned short* __restrict__ G1) {
  const int tid = threadIdx.x;
  const int t = blockIdx.x >> 1, half = blockIdx.x & 1;
  const int w = tid >> 6, l = tid & 63;
  const int m0 = w * 16;
  const int kof = (l >> 4) * 8;
  bf16x8 av[16];
#pragma unroll
  for (int ks = 0; ks < 16; ++ks)
    av[ks] = *reinterpret_cast<const bf16x8*>(
        xb + ((size_t)t * 64 + m0 + (l & 15)) * H_SIZE + ks * 32 + kof);
  const int crow0 = m0 + ((l >> 4) << 2);
  const int ln = l & 15;

  bf16x8 p0[8], p1[8];
  loadB8(p0, W1b, half * 1024 + ln, 0, kof);
  for (int ct = 0; ct < 64; ++ct) {
    const int vc = half * 1024 + ct * 16 + ln;
    const int vcn = half * 1024 + ((ct < 63) ? ct + 1 : ct) * 16 + ln;
    f32x4 acc = {0.f, 0.f, 0.f, 0.f};
    loadB8(p1, W1b, vc, 1, kof);
#pragma unroll
    for (int ks = 0; ks < 8; ++ks)
      acc = __builtin_amdgcn_mfma_f32_16x16x32_bf16(av[ks], p0[ks], acc, 0, 0, 0);
    loadB8(p0, W1b, vcn, 0, kof);
#pragma unroll
    for (int ks = 0; ks < 8; ++ks)
      acc = __builtin_amdgcn_mfma_f32_16x16x32_bf16(av[8 + ks], p1[ks], acc, 0, 0, 0);
    float bb = b1[vc];
#pragma unroll
    for (int r = 0; r < 4; ++r)
      G1[((size_t)t * 64 + crow0 + r) * NG + vc] = f2bf(acc[r] + bb);
  }
}

// ---------------- barrier-free dataflow MFMA 2-layer LSTM ----------------
// Blocks 0..63: layer 1, own 8 h-cols. Blocks 64..127: layer 2.
// h1all/h2all: bf16 [T][64][512] full history, sentinel-prefilled.
// Polling is branch-free full-batch: every pass reloads ALL chunks
// back-to-back (one MALL round trip per pass), then checks.
__global__ __launch_bounds__(RTH, 1) void recur_k(
    const float* __restrict__ W1, const float* __restrict__ W2,
    const float* __restrict__ b2, const unsigned short* __restrict__ G1,
    const unsigned short* __restrict__ hzero,
    unsigned short* __restrict__ h1all, unsigned short* __restrict__ h2all)
{
  __shared__ short wlds[2 * 32 * 64 * 8];   // 64 KB (L1 uses half)
  __shared__ float gbuf[64][32];            // 8 KB

  const int tid  = threadIdx.x;
  const int bid  = blockIdx.x;
  const bool isL2 = (bid >= 64);
  const int h0   = (isL2 ? bid - 64 : bid) * 8;
  const int w    = tid >> 6, l = tid & 63;
  const int NK   = isL2 ? 32 : 16;

  // ---- one-time weight preload, bf16 in B-frag order ----
  {
    const float* Wsrc = isL2 ? W2 : (W1 + (size_t)H_SIZE * NG);
    for (int idx = tid; idx < 2 * NK * 64; idx += RTH) {
      int lane = idx & 63;
      int ks   = (idx >> 6) % NK;
      int ng   = (idx >> 6) / NK;
      int n    = lane & 15;
      int col  = (n & 3) * H_SIZE + h0 + ng * 4 + (n >> 2);
      int kb   = ks * 32 + (lane >> 4) * 8;
      short* dst = &wlds[((size_t)(ng * NK + ks) * 64 + lane) * 8];
#pragma unroll
      for (int e = 0; e < 8; ++e)
        dst[e] = (short)f2bf(Wsrc[(size_t)(kb + e) * NG + col]);
    }
  }

  // pointwise mapping: thread = pb*4+pq handles (b=pb, cols h0+2pq, h0+2pq+1)
  const int pb = tid >> 2, pq = tid & 3;
  float cst[2] = {0.f, 0.f};
  float bias2[2][4];
  if (isL2) {
#pragma unroll
    for (int hh = 0; hh < 2; ++hh)
#pragma unroll
      for (int g = 0; g < 4; ++g)
        bias2[hh][g] = b2[g * H_SIZE + h0 + 2 * pq + hh];
  }
  __syncthreads();

  const int arow = w * 16 + (l & 15);
  const int kof  = (l >> 4) * 8;

  for (int t = 0; t < T_SIZE; ++t) {
    // prefetch G1 gate addends (L1) - independent of the h poll
    unsigned g1v[4];
    if (!isL2) {
      const unsigned short* gp = G1 + ((size_t)t * 64 + pb) * NG + h0 + 2 * pq;
#pragma unroll
      for (int gg = 0; gg < 4; ++gg)
        g1v[gg] = *reinterpret_cast<const unsigned*>(gp + gg * H_SIZE);
    }

    f32x4 acc0 = {0.f, 0.f, 0.f, 0.f};
    f32x4 acc1 = {0.f, 0.f, 0.f, 0.f};

    if (!isL2) {
      const unsigned short* a1 = ((t == 0) ? hzero : h1all + (size_t)(t - 1) * HB)
                                 + (size_t)arow * H_SIZE + kof;
      bf16x8 av[16];
      // branch-free batched poll: reload ALL 16 chunks each pass
      unsigned pend;
      do {
#pragma unroll
        for (int ks = 0; ks < 16; ++ks) av[ks] = aload16(a1 + ks * 32);
        pend = 0;
#pragma unroll
        for (int ks = 0; ks < 16; ++ks) pend |= has_sent(av[ks]);
      } while (pend);
#pragma unroll
      for (int ks = 0; ks < 16; ++ks) {
        bf16x8 bv0 = *reinterpret_cast<const bf16x8*>(&wlds[((size_t)(0 * 16 + ks) * 64 + l) * 8]);
        bf16x8 bv1 = *reinterpret_cast<const bf16x8*>(&wlds[((size_t)(1 * 16 + ks) * 64 + l) * 8]);
        acc0 = __builtin_amdgcn_mfma_f32_16x16x32_bf16(av[ks], bv0, acc0, 0, 0, 0);
        acc1 = __builtin_amdgcn_mfma_f32_16x16x32_bf16(av[ks], bv1, acc1, 0, 0, 0);
      }
    } else {
      const unsigned short* a2 = ((t == 0) ? hzero : h2all + (size_t)(t - 1) * HB)
                                 + (size_t)arow * H_SIZE + kof;
      const unsigned short* a1 = h1all + (size_t)t * HB + (size_t)arow * H_SIZE + kof;
      bf16x8 av2[16], av1[16];
      // combined batched poll over both groups (32 chunks per pass)
      unsigned pend;
      do {
#pragma unroll
        for (int ks = 0; ks < 16; ++ks) av2[ks] = aload16(a2 + ks * 32);
#pragma unroll
        for (int ks = 0; ks < 16; ++ks) av1[ks] = aload16(a1 + ks * 32);
        pend = 0;
#pragma unroll
        for (int ks = 0; ks < 16; ++ks) pend |= has_sent(av2[ks]) | has_sent(av1[ks]);
      } while (pend);
#pragma unroll
      for (int ks = 0; ks < 16; ++ks) {
        bf16x8 bv0 = *reinterpret_cast<const bf16x8*>(&wlds[((size_t)(0 * 32 + 16 + ks) * 64 + l) * 8]);
        bf16x8 bv1 = *reinterpret_cast<const bf16x8*>(&wlds[((size_t)(1 * 32 + 16 + ks) * 64 + l) * 8]);
        acc0 = __builtin_amdgcn_mfma_f32_16x16x32_bf16(av2[ks], bv0, acc0, 0, 0, 0);
        acc1 = __builtin_amdgcn_mfma_f32_16x16x32_bf16(av2[ks], bv1, acc1, 0, 0, 0);
      }
#pragma unroll
      for (int ks = 0; ks < 16; ++ks) {
        bf16x8 bv0 = *reinterpret_cast<const bf16x8*>(&wlds[((size_t)(0 * 32 + ks) * 64 + l) * 8]);
        bf16x8 bv1 = *reinterpret_cast<const bf16x8*>(&wlds[((size_t)(1 * 32 + ks) * 64 + l) * 8]);
        acc0 = __builtin_amdgcn_mfma_f32_16x16x32_bf16(av1[ks], bv0, acc0, 0, 0, 0);
        acc1 = __builtin_amdgcn_mfma_f32_16x16x32_bf16(av1[ks], bv1, acc1, 0, 0, 0);
      }
    }

    // C -> gbuf: row = w*16 + (l>>4)*4 + r, col = ng*16 + (l&15)
    {
      const int crow = w * 16 + ((l >> 4) << 2);
      const int ccol = l & 15;
#pragma unroll
      for (int r = 0; r < 4; ++r) {
        gbuf[crow + r][ccol]      = acc0[r];
        gbuf[crow + r][16 + ccol] = acc1[r];
      }
    }
    __syncthreads();

    // pointwise: two adjacent h-cols per thread -> one packed u32 sc1 store
    unsigned short hbv[2];
#pragma unroll
    for (int hh = 0; hh < 2; ++hh) {
      const int hl = 2 * pq + hh;
      const int ng = hl >> 2, jj = hl & 3;
      float g[4];
#pragma unroll
      for (int gg = 0; gg < 4; ++gg) g[gg] = gbuf[pb][ng * 16 + jj * 4 + gg];
      if (!isL2) {
#pragma unroll
        for (int gg = 0; gg < 4; ++gg)
          g[gg] += bf2f((unsigned short)(g1v[gg] >> (16 * hh)));
      } else {
#pragma unroll
        for (int gg = 0; gg < 4; ++gg) g[gg] += bias2[hh][gg];
      }
      float cn = cst[hh] * sigf(g[2]) + sigf(g[0]) * tanhf_fast(g[1]);
      float hn = tanhf_fast(cn) * sigf(g[3]);
      cst[hh] = cn;
      hbv[hh] = f2bf(hn);
    }
    unsigned pack = (unsigned)hbv[0] | ((unsigned)hbv[1] << 16);
    unsigned short* base = (isL2 ? h2all : h1all) + (size_t)t * HB
                           + (size_t)pb * H_SIZE + h0 + 2 * pq;
    __hip_atomic_store((unsigned*)base, pack, __ATOMIC_RELAXED,
                       __HIP_MEMORY_SCOPE_AGENT);
    __syncthreads();   // protect gbuf for next iteration
  }
}

// ---------------- MFMA fused logits + online logsumexp (B-dbuf, branchless) ----------------
__global__ __launch_bounds__(256) void ce_mfma_k(const unsigned short* __restrict__ outs,
                                                 const unsigned short* __restrict__ Wvb,
                                                 const float* __restrict__ bvb,
                                                 const int* __restrict__ tgts,
                                                 float* __restrict__ pmx,
                                                 float* __restrict__ psm,
                                                 float* __restrict__ ptg) {
  const int tid = threadIdx.x;
  const int t = blockIdx.x >> 1, half = blockIdx.x & 1;
  const int w = tid >> 6, l = tid & 63;
  const int m0 = w * 16;
  const int kof = (l >> 4) * 8;
  const int ln = l & 15;
  bf16x8 av[16];
#pragma unroll
  for (int ks = 0; ks < 16; ++ks)
    av[ks] = *reinterpret_cast<const bf16x8*>(
        outs + ((size_t)t * 64 + m0 + ln) * H_SIZE + ks * 32 + kof);
  int lbl[4];
#pragma unroll
  for (int r = 0; r < 4; ++r)
    lbl[r] = tgts[(size_t)(m0 + ((l >> 4) << 2) + r) * T_SIZE + t];

  float mx[4] = {-1e30f, -1e30f, -1e30f, -1e30f};
  float sm[4] = {0.f, 0.f, 0.f, 0.f};
  float tg[4] = {0.f, 0.f, 0.f, 0.f};

  bf16x8 p0[8], p1[8];
  loadB8(p0, Wvb, half * 4000 + ln, 0, kof);
  for (int ct = 0; ct < 250; ++ct) {
    const int vc = half * 4000 + ct * 16 + ln;
    const int vcn = half * 4000 + ((ct < 249) ? ct + 1 : ct) * 16 + ln;
    f32x4 acc = {0.f, 0.f, 0.f, 0.f};
    loadB8(p1, Wvb, vc, 1, kof);
#pragma unroll
    for (int ks = 0; ks < 8; ++ks)
      acc = __builtin_amdgcn_mfma_f32_16x16x32_bf16(av[ks], p0[ks], acc, 0, 0, 0);
    loadB8(p0, Wvb, vcn, 0, kof);
#pragma unroll
    for (int ks = 0; ks < 8; ++ks)
      acc = __builtin_amdgcn_mfma_f32_16x16x32_bf16(av[8 + ks], p1[ks], acc, 0, 0, 0);

    float bb = bvb[vc];
#pragma unroll
    for (int r = 0; r < 4; ++r) {
      float lg = acc[r] + bb;
      tg[r] += (vc == lbl[r]) ? lg : 0.f;
      float nm = fmaxf(mx[r], lg);
      sm[r] = sm[r] * __expf(mx[r] - nm) + __expf(lg - nm);
      mx[r] = nm;
    }
  }

#pragma unroll
  for (int off = 1; off <= 8; off <<= 1) {
#pragma unroll
    for (int r = 0; r < 4; ++r) {
      float om = __shfl_xor(mx[r], off, 64);
      float os = __shfl_xor(sm[r], off, 64);
      float ot = __shfl_xor(tg[r], off, 64);
      float nm = fmaxf(mx[r], om);
      sm[r] = sm[r] * __expf(mx[r] - nm) + os * __expf(om - nm);
      mx[r] = nm;
      tg[r] += ot;
    }
  }
  if (ln == 0) {
    int idx = (t * 2 + half) * 64 + m0 + ((l >> 4) << 2);
#pragma unroll
    for (int r = 0; r < 4; ++r) {
      pmx[idx + r] = mx[r]; psm[idx + r] = sm[r]; ptg[idx + r] = tg[r];
    }
  }
}

// ---------------- merge halves, per-row loss, sum ----------------
__global__ __launch_bounds__(256) void cemerge_k(const float* __restrict__ pmx,
                                                 const float* __restrict__ psm,
                                                 const float* __restrict__ ptg,
                                                 float* __restrict__ accum) {
  int g = blockIdx.x * 256 + threadIdx.x;   // 0..8191
  int t = g >> 6, row = g & 63;
  int i0 = (t * 2) * 64 + row, i1 = (t * 2 + 1) * 64 + row;
  float m0 = pmx[i0], m1 = pmx[i1];
  float M = fmaxf(m0, m1);
  float S = psm[i0] * __expf(m0 - M) + psm[i1] * __expf(m1 - M);
  float loss = M + logf(S) - (ptg[i0] + ptg[i1]);
#pragma unroll
  for (int off = 32; off >= 1; off >>= 1)
    loss += __shfl_xor(loss, off, 64);
  if ((threadIdx.x & 63) == 0) atomicAdd(accum, loss);
}

__global__ void finish_k(const float* __restrict__ accum, float* __restrict__ out) {
  out[0] = accum[0] * (1.f / (float)NROW);
}

// ---------------- launcher ----------------
extern "C" void kernel_launch(void* const* d_in, const int* in_sizes, int n_in,
                              void* d_out, int out_size, void* d_ws, size_t ws_size,
                              hipStream_t stream) {
  const int*   ids  = (const int*)  d_in[0];
  const int*   tgts = (const int*)  d_in[1];
  const float* emb  = (const float*)d_in[2];
  const float* W1   = (const float*)d_in[3];
  const float* b1   = (const float*)d_in[4];
  const float* W2   = (const float*)d_in[5];
  const float* b2   = (const float*)d_in[6];
  const float* Wv   = (const float*)d_in[7];
  const float* bv   = (const float*)d_in[8];
  float* out = (float*)d_out;

  // ws layout (bytes). REGION_A is time-shared: xb (pre-recur) -> h1all
  // (recur) -> Wvb (CE).
  char* ws = (char*)d_ws;
  unsigned short* G1    = (unsigned short*)(ws);                 // 33,554,432
  unsigned short* outsb = (unsigned short*)(ws + 33554432);      //  8,388,608 (=h2all)
  unsigned short* regA  = (unsigned short*)(ws + 41943040);      //  8,388,608
  unsigned short* xb    = regA;
  unsigned short* h1all = regA;
  unsigned short* Wvb   = regA;
  unsigned short* W1b   = (unsigned short*)(ws + 50331648);      //  2,097,152
  unsigned short* hzero = (unsigned short*)(ws + 52428800);      //     65,536
  float*          accum = (float*)         (ws + 52494336);      //          4
  float*          pmx   = (float*)         (ws + 52494400);      //     65,536
  float*          psm   = (float*)         (ws + 52559936);      //     65,536
  float*          ptg   = (float*)         (ws + 52625472);      //     65,536

  // zeros: hzero (16384 u32) + accum (1 u32, adjacent region start)
  fill_k<<<65, 256, 0, stream>>>((unsigned*)hzero, 0u, 16385);

  xgather_k<<<2048, 256, 0, stream>>>(ids, emb, xb);
  trans_k<<<256, 256, 0, stream>>>(W1, W1b, NG, 32);          // W1[0:512,:] -> W1b
  gemm1mm_k<<<256, 256, 0, stream>>>(xb, W1b, b1, G1);        // xb dead after this

  // sentinel-fill h1all (reuses xb region) and h2all/outs
  fill_k<<<8192, 256, 0, stream>>>((unsigned*)h1all, SENT, 2097152);
  fill_k<<<8192, 256, 0, stream>>>((unsigned*)outsb, SENT, 2097152);

  {
    void* args[] = { (void*)&W1, (void*)&W2, (void*)&b2, (void*)&G1,
                     (void*)&hzero, (void*)&h1all, (void*)&outsb };
    hipError_t e = hipLaunchCooperativeKernel((const void*)recur_k,
                                              dim3(RBLK), dim3(RTH),
                                              args, 0, stream);
    if (e != hipSuccess) {
      // plain launch: 128 blocks on 256 CUs -> co-resident
      recur_k<<<dim3(RBLK), dim3(RTH), 0, stream>>>(W1, W2, b2, G1, hzero,
                                                    h1all, outsb);
    }
  }

  trans_k<<<1000, 256, 0, stream>>>(Wv, Wvb, V_SIZE, 125);    // Wv -> Wvb (h1all dead)

  ce_mfma_k<<<256, 256, 0, stream>>>(outsb, Wvb, bv, tgts, pmx, psm, ptg);
  cemerge_k<<<32, 256, 0, stream>>>(pmx, psm, ptg, accum);
  finish_k<<<1, 1, 0, stream>>>(accum, out);
}

// Round 8
// 1980.522 us; speedup vs baseline: 1.2027x; 1.2027x over previous
//
#include <hip/hip_runtime.h>
#include <hip/hip_bf16.h>

// CharRNN: 2-layer LSTM LM + softmax CE on MI355X (gfx950).
// Round 8: merged-layer dataflow recurrence. 64 blocks own 8 h-cols of BOTH
// layers (W1r+W2 slices in LDS, 112 KB). Per step: one sentinel-poll of
// {h1[t-1], h2[t-2]}, L1 compute, h1[t] store EARLY, then L2(t-1) compute
// covers h1's MALL propagation. Per-chunk re-poll (r6 shape) + s_sleep.
// CE/gemm1 keep r7's B-dbuf MFMA pipelines.
// dims: V=8000, B=64, T=128, H=512.

#define V_SIZE 8000
#define B_SIZE 64
#define T_SIZE 128
#define H_SIZE 512
#define NROW   (B_SIZE * T_SIZE)     // 8192
#define NG     (4 * H_SIZE)          // 2048 gate columns
#define HB     (H_SIZE * B_SIZE)     // one h time-slice (bf16 elems)
#define RBLK   64                    // recurrence grid (merged blocks)
#define RTH    256                   // recurrence block size
#define SENT   0x7FFF7FFFu

typedef __attribute__((ext_vector_type(8))) short bf16x8;
typedef __attribute__((ext_vector_type(8))) unsigned short u16x8;
typedef __attribute__((ext_vector_type(4))) float f32x4;

// ---------- bf16 helpers (raw ushort storage) ----------
__device__ __forceinline__ float bf2f(unsigned short u) {
  union { unsigned int i; float f; } x; x.i = ((unsigned int)u) << 16; return x.f;
}
__device__ __forceinline__ unsigned short f2bf(float f) {
  union { float f; unsigned int i; } x; x.f = f;
  unsigned int r = x.i + 0x7fffu + ((x.i >> 16) & 1u);
  return (unsigned short)(r >> 16);
}
__device__ __forceinline__ float sigf(float v) { return 1.f / (1.f + __expf(-v)); }
__device__ __forceinline__ float tanhf_fast(float v) {
  return 1.f - 2.f / (__expf(2.f * v) + 1.f);
}

// agent-scope (MALL-coherent) 16B A-fragment load as 2x u64
__device__ __forceinline__ bf16x8 aload16(const unsigned short* p) {
  unsigned long long lo = __hip_atomic_load((const unsigned long long*)p,
                                            __ATOMIC_RELAXED, __HIP_MEMORY_SCOPE_AGENT);
  unsigned long long hi = __hip_atomic_load((const unsigned long long*)(p + 4),
                                            __ATOMIC_RELAXED, __HIP_MEMORY_SCOPE_AGENT);
  union { unsigned long long v[2]; bf16x8 b; } u;
  u.v[0] = lo; u.v[1] = hi;
  return u.b;
}
__device__ __forceinline__ unsigned has_sent(bf16x8 v) {
  union { bf16x8 b; unsigned u[4]; } x; x.b = v;
  return (unsigned)((x.u[0] == SENT) | (x.u[1] == SENT) |
                    (x.u[2] == SENT) | (x.u[3] == SENT));
}

// ---------------- fill ----------------
__global__ void fill_k(unsigned* __restrict__ p, unsigned v, int n) {
  int i = blockIdx.x * 256 + threadIdx.x;
  if (i < n) p[i] = v;
}

// ---------------- embedding gather -> bf16 x [8192 rows=t*64+b][512] ----------------
__global__ __launch_bounds__(256) void xgather_k(const int* __restrict__ ids,
                                                 const float* __restrict__ emb,
                                                 unsigned short* __restrict__ xb) {
  int g = blockIdx.x * 256 + threadIdx.x;   // 8192 rows x 64 chunks of 8
  int r = g >> 6, c = g & 63;
  int t = r >> 6, b = r & 63;
  int id = ids[(size_t)b * T_SIZE + t];
  const float4* s4 = reinterpret_cast<const float4*>(emb + (size_t)id * H_SIZE + c * 8);
  float4 v0 = s4[0], v1 = s4[1];
  u16x8 o;
  o[0] = f2bf(v0.x); o[1] = f2bf(v0.y); o[2] = f2bf(v0.z); o[3] = f2bf(v0.w);
  o[4] = f2bf(v1.x); o[5] = f2bf(v1.y); o[6] = f2bf(v1.z); o[7] = f2bf(v1.w);
  *reinterpret_cast<u16x8*>(xb + (size_t)r * H_SIZE + c * 8) = o;
}

// ---------------- f32 [K][N] -> bf16 [N][K] transpose (64x64 tiles) ----------------
__global__ __launch_bounds__(256) void trans_k(const float* __restrict__ src,
                                               unsigned short* __restrict__ dst,
                                               int src_ld, int n_tiles) {
  __shared__ float tile[64][65];
  const int tid = threadIdx.x;
  const int kt = blockIdx.x / n_tiles, nt = blockIdx.x % n_tiles;
#pragma unroll
  for (int q = 0; q < 16; ++q) {
    int f = tid + 256 * q;
    int r = f >> 6, c = f & 63;
    tile[r][c] = src[(size_t)(kt * 64 + r) * src_ld + nt * 64 + c];
  }
  __syncthreads();
#pragma unroll
  for (int q = 0; q < 2; ++q) {
    int u = tid + 256 * q;
    int n = u >> 3, kg = u & 7;
    u16x8 o;
#pragma unroll
    for (int e = 0; e < 8; ++e) o[e] = f2bf(tile[kg * 8 + e][n]);
    *reinterpret_cast<u16x8*>(dst + (size_t)(nt * 64 + n) * 512 + kt * 64 + kg * 8) = o;
  }
}

// load 8 B-fragments (one K-half) for column vc from a [N][512] bf16 matrix
__device__ __forceinline__ void loadB8(bf16x8* p, const unsigned short* Wb,
                                       int vc, int kh, int kof) {
#pragma unroll
  for (int ks = 0; ks < 8; ++ks)
    p[ks] = *reinterpret_cast<const bf16x8*>(
        Wb + (size_t)vc * 512 + (kh * 8 + ks) * 32 + kof);
}

// ---------------- G1 = x @ W1x + b1 (MFMA, B-dbuf), bf16 out [t][b][2048] ----------------
__global__ __launch_bounds__(256) void gemm1mm_k(const unsigned short* __restrict__ xb,
                                                 const unsigned short* __restrict__ W1b,
                                                 const float* __restrict__ b1,
                                                 unsigned short* __restrict__ G1) {
  const int tid = threadIdx.x;
  const int t = blockIdx.x >> 1, half = blockIdx.x & 1;
  const int w = tid >> 6, l = tid & 63;
  const int m0 = w * 16;
  const int kof = (l >> 4) * 8;
  bf16x8 av[16];
#pragma unroll
  for (int ks = 0; ks < 16; ++ks)
    av[ks] = *reinterpret_cast<const bf16x8*>(
        xb + ((size_t)t * 64 + m0 + (l & 15)) * H_SIZE + ks * 32 + kof);
  const int crow0 = m0 + ((l >> 4) << 2);
  const int ln = l & 15;

  bf16x8 p0[8], p1[8];
  loadB8(p0, W1b, half * 1024 + ln, 0, kof);
  for (int ct = 0; ct < 64; ++ct) {
    const int vc = half * 1024 + ct * 16 + ln;
    const int vcn = half * 1024 + ((ct < 63) ? ct + 1 : ct) * 16 + ln;
    f32x4 acc = {0.f, 0.f, 0.f, 0.f};
    loadB8(p1, W1b, vc, 1, kof);
#pragma unroll
    for (int ks = 0; ks < 8; ++ks)
      acc = __builtin_amdgcn_mfma_f32_16x16x32_bf16(av[ks], p0[ks], acc, 0, 0, 0);
    loadB8(p0, W1b, vcn, 0, kof);
#pragma unroll
    for (int ks = 0; ks < 8; ++ks)
      acc = __builtin_amdgcn_mfma_f32_16x16x32_bf16(av[8 + ks], p1[ks], acc, 0, 0, 0);
    float bb = b1[vc];
#pragma unroll
    for (int r = 0; r < 4; ++r)
      G1[((size_t)t * 64 + crow0 + r) * NG + vc] = f2bf(acc[r] + bb);
  }
}

// ---------------- merged-layer dataflow MFMA 2-layer LSTM ----------------
// 64 blocks; block owns 8 h-cols of BOTH layers. Per step t:
//   poll {h1[t-1], h2[t-2]} -> L1(t) -> store h1[t] -> L2(t-1) -> store h2[t-1]
__global__ __launch_bounds__(RTH, 1) void recur_k(
    const float* __restrict__ W1, const float* __restrict__ W2,
    const float* __restrict__ b2, const unsigned short* __restrict__ G1,
    const unsigned short* __restrict__ hzero,
    unsigned short* __restrict__ h1all, unsigned short* __restrict__ h2all)
{
  __shared__ short wlds1[2 * 16 * 64 * 8];  // 32 KB  W1 recurrent slice
  __shared__ short wlds2[2 * 32 * 64 * 8];  // 64 KB  W2 slice
  __shared__ float gbA[64][32];             // 8 KB   L1 gates
  __shared__ float gbB[64][32];             // 8 KB   L2 gates

  const int tid = threadIdx.x;
  const int bid = blockIdx.x;
  const int h0  = bid * 8;
  const int w   = tid >> 6, l = tid & 63;

  // ---- one-time weight preload, bf16 in B-frag order ----
  {
    const float* Wsrc = W1 + (size_t)H_SIZE * NG;
    for (int idx = tid; idx < 2 * 16 * 64; idx += RTH) {
      int lane = idx & 63;
      int ks   = (idx >> 6) % 16;
      int ng   = (idx >> 6) / 16;
      int n    = lane & 15;
      int col  = (n & 3) * H_SIZE + h0 + ng * 4 + (n >> 2);
      int kb   = ks * 32 + (lane >> 4) * 8;
      short* dst = &wlds1[((size_t)(ng * 16 + ks) * 64 + lane) * 8];
#pragma unroll
      for (int e = 0; e < 8; ++e)
        dst[e] = (short)f2bf(Wsrc[(size_t)(kb + e) * NG + col]);
    }
    for (int idx = tid; idx < 2 * 32 * 64; idx += RTH) {
      int lane = idx & 63;
      int ks   = (idx >> 6) % 32;
      int ng   = (idx >> 6) / 32;
      int n    = lane & 15;
      int col  = (n & 3) * H_SIZE + h0 + ng * 4 + (n >> 2);
      int kb   = ks * 32 + (lane >> 4) * 8;
      short* dst = &wlds2[((size_t)(ng * 32 + ks) * 64 + lane) * 8];
#pragma unroll
      for (int e = 0; e < 8; ++e)
        dst[e] = (short)f2bf(W2[(size_t)(kb + e) * NG + col]);
    }
  }

  // pointwise mapping: thread = pb*4+pq handles (b=pb, cols h0+2pq, h0+2pq+1)
  const int pb = tid >> 2, pq = tid & 3;
  float c1[2] = {0.f, 0.f}, c2[2] = {0.f, 0.f};
  float bias2[2][4];
#pragma unroll
  for (int hh = 0; hh < 2; ++hh)
#pragma unroll
    for (int g = 0; g < 4; ++g)
      bias2[hh][g] = b2[g * H_SIZE + h0 + 2 * pq + hh];
  __syncthreads();

  const int arow = w * 16 + (l & 15);
  const int kof  = (l >> 4) * 8;

  for (int t = 0; t <= T_SIZE; ++t) {
    // G1 gate addends for L1(t)
    unsigned g1v[4];
    if (t < T_SIZE) {
      const unsigned short* gp = G1 + ((size_t)t * 64 + pb) * NG + h0 + 2 * pq;
#pragma unroll
      for (int gg = 0; gg < 4; ++gg)
        g1v[gg] = *reinterpret_cast<const unsigned*>(gp + gg * H_SIZE);
    }

    // ---- one poll for both operands: h1[t-1] and h2[t-2] ----
    const unsigned short* a1 = ((t == 0) ? hzero : h1all + (size_t)(t - 1) * HB)
                               + (size_t)arow * H_SIZE + kof;
    const unsigned short* a2 = ((t < 2) ? hzero : h2all + (size_t)(t - 2) * HB)
                               + (size_t)arow * H_SIZE + kof;
    bf16x8 av1[16], av2[16];
    unsigned p1m = 0, p2m = 0;
#pragma unroll
    for (int ks = 0; ks < 16; ++ks) av1[ks] = aload16(a1 + ks * 32);
#pragma unroll
    for (int ks = 0; ks < 16; ++ks) av2[ks] = aload16(a2 + ks * 32);
#pragma unroll
    for (int ks = 0; ks < 16; ++ks) {
      p1m |= has_sent(av1[ks]) << ks;
      p2m |= has_sent(av2[ks]) << ks;
    }
    while (p1m | p2m) {
      __builtin_amdgcn_s_sleep(2);
#pragma unroll
      for (int ks = 0; ks < 16; ++ks)
        if ((p1m >> ks) & 1) {
          av1[ks] = aload16(a1 + ks * 32);
          if (!has_sent(av1[ks])) p1m &= ~(1u << ks);
        }
#pragma unroll
      for (int ks = 0; ks < 16; ++ks)
        if ((p2m >> ks) & 1) {
          av2[ks] = aload16(a2 + ks * 32);
          if (!has_sent(av2[ks])) p2m &= ~(1u << ks);
        }
    }

    // ================= L1(t): MFMA + pointwise + EARLY h1 store =================
    if (t < T_SIZE) {
      f32x4 acc0 = {0.f, 0.f, 0.f, 0.f};
      f32x4 acc1 = {0.f, 0.f, 0.f, 0.f};
#pragma unroll
      for (int ks = 0; ks < 16; ++ks) {
        bf16x8 bv0 = *reinterpret_cast<const bf16x8*>(&wlds1[((size_t)(0 * 16 + ks) * 64 + l) * 8]);
        bf16x8 bv1 = *reinterpret_cast<const bf16x8*>(&wlds1[((size_t)(1 * 16 + ks) * 64 + l) * 8]);
        acc0 = __builtin_amdgcn_mfma_f32_16x16x32_bf16(av1[ks], bv0, acc0, 0, 0, 0);
        acc1 = __builtin_amdgcn_mfma_f32_16x16x32_bf16(av1[ks], bv1, acc1, 0, 0, 0);
      }
      {
        const int crow = w * 16 + ((l >> 4) << 2);
        const int ccol = l & 15;
#pragma unroll
        for (int r = 0; r < 4; ++r) {
          gbA[crow + r][ccol]      = acc0[r];
          gbA[crow + r][16 + ccol] = acc1[r];
        }
      }
      __syncthreads();
      unsigned short hbv[2];
#pragma unroll
      for (int hh = 0; hh < 2; ++hh) {
        const int hl = 2 * pq + hh;
        const int ng = hl >> 2, jj = hl & 3;
        float g[4];
#pragma unroll
        for (int gg = 0; gg < 4; ++gg)
          g[gg] = gbA[pb][ng * 16 + jj * 4 + gg] +
                  bf2f((unsigned short)(g1v[gg] >> (16 * hh)));
        float cn = c1[hh] * sigf(g[2]) + sigf(g[0]) * tanhf_fast(g[1]);
        float hn = tanhf_fast(cn) * sigf(g[3]);
        c1[hh] = cn;
        hbv[hh] = f2bf(hn);
      }
      unsigned pack = (unsigned)hbv[0] | ((unsigned)hbv[1] << 16);
      __hip_atomic_store((unsigned*)(h1all + (size_t)t * HB + (size_t)pb * H_SIZE
                                     + h0 + 2 * pq),
                         pack, __ATOMIC_RELAXED, __HIP_MEMORY_SCOPE_AGENT);
    }

    // ================= L2(t-1): MFMA + pointwise + h2 store =================
    if (t >= 1) {
      f32x4 acc0 = {0.f, 0.f, 0.f, 0.f};
      f32x4 acc1 = {0.f, 0.f, 0.f, 0.f};
#pragma unroll
      for (int ks = 0; ks < 16; ++ks) {   // h2[t-2] rows 512..1023
        bf16x8 bv0 = *reinterpret_cast<const bf16x8*>(&wlds2[((size_t)(0 * 32 + 16 + ks) * 64 + l) * 8]);
        bf16x8 bv1 = *reinterpret_cast<const bf16x8*>(&wlds2[((size_t)(1 * 32 + 16 + ks) * 64 + l) * 8]);
        acc0 = __builtin_amdgcn_mfma_f32_16x16x32_bf16(av2[ks], bv0, acc0, 0, 0, 0);
        acc1 = __builtin_amdgcn_mfma_f32_16x16x32_bf16(av2[ks], bv1, acc1, 0, 0, 0);
      }
#pragma unroll
      for (int ks = 0; ks < 16; ++ks) {   // h1[t-1] rows 0..511
        bf16x8 bv0 = *reinterpret_cast<const bf16x8*>(&wlds2[((size_t)(0 * 32 + ks) * 64 + l) * 8]);
        bf16x8 bv1 = *reinterpret_cast<const bf16x8*>(&wlds2[((size_t)(1 * 32 + ks) * 64 + l) * 8]);
        acc0 = __builtin_amdgcn_mfma_f32_16x16x32_bf16(av1[ks], bv0, acc0, 0, 0, 0);
        acc1 = __builtin_amdgcn_mfma_f32_16x16x32_bf16(av1[ks], bv1, acc1, 0, 0, 0);
      }
      {
        const int crow = w * 16 + ((l >> 4) << 2);
        const int ccol = l & 15;
#pragma unroll
        for (int r = 0; r < 4; ++r) {
          gbB[crow + r][ccol]      = acc0[r];
          gbB[crow + r][16 + ccol] = acc1[r];
        }
      }
      __syncthreads();
      unsigned short hbv[2];
#pragma unroll
      for (int hh = 0; hh < 2; ++hh) {
        const int hl = 2 * pq + hh;
        const int ng = hl >> 2, jj = hl & 3;
        float g[4];
#pragma unroll
        for (int gg = 0; gg < 4; ++gg)
          g[gg] = gbB[pb][ng * 16 + jj * 4 + gg] + bias2[hh][gg];
        float cn = c2[hh] * sigf(g[2]) + sigf(g[0]) * tanhf_fast(g[1]);
        float hn = tanhf_fast(cn) * sigf(g[3]);
        c2[hh] = cn;
        hbv[hh] = f2bf(hn);
      }
      unsigned pack = (unsigned)hbv[0] | ((unsigned)hbv[1] << 16);
      __hip_atomic_store((unsigned*)(h2all + (size_t)(t - 1) * HB
                                     + (size_t)pb * H_SIZE + h0 + 2 * pq),
                         pack, __ATOMIC_RELAXED, __HIP_MEMORY_SCOPE_AGENT);
    }

    __syncthreads();   // protect gbA/gbB for next iteration
  }
}

// ---------------- MFMA fused logits + online logsumexp (B-dbuf, branchless) ----------------
__global__ __launch_bounds__(256) void ce_mfma_k(const unsigned short* __restrict__ outs,
                                                 const unsigned short* __restrict__ Wvb,
                                                 const float* __restrict__ bvb,
                                                 const int* __restrict__ tgts,
                                                 float* __restrict__ pmx,
                                                 float* __restrict__ psm,
                                                 float* __restrict__ ptg) {
  const int tid = threadIdx.x;
  const int t = blockIdx.x >> 1, half = blockIdx.x & 1;
  const int w = tid >> 6, l = tid & 63;
  const int m0 = w * 16;
  const int kof = (l >> 4) * 8;
  const int ln = l & 15;
  bf16x8 av[16];
#pragma unroll
  for (int ks = 0; ks < 16; ++ks)
    av[ks] = *reinterpret_cast<const bf16x8*>(
        outs + ((size_t)t * 64 + m0 + ln) * H_SIZE + ks * 32 + kof);
  int lbl[4];
#pragma unroll
  for (int r = 0; r < 4; ++r)
    lbl[r] = tgts[(size_t)(m0 + ((l >> 4) << 2) + r) * T_SIZE + t];

  float mx[4] = {-1e30f, -1e30f, -1e30f, -1e30f};
  float sm[4] = {0.f, 0.f, 0.f, 0.f};
  float tg[4] = {0.f, 0.f, 0.f, 0.f};

  bf16x8 p0[8], p1[8];
  loadB8(p0, Wvb, half * 4000 + ln, 0, kof);
  for (int ct = 0; ct < 250; ++ct) {
    const int vc = half * 4000 + ct * 16 + ln;
    const int vcn = half * 4000 + ((ct < 249) ? ct + 1 : ct) * 16 + ln;
    f32x4 acc = {0.f, 0.f, 0.f, 0.f};
    loadB8(p1, Wvb, vc, 1, kof);
#pragma unroll
    for (int ks = 0; ks < 8; ++ks)
      acc = __builtin_amdgcn_mfma_f32_16x16x32_bf16(av[ks], p0[ks], acc, 0, 0, 0);
    loadB8(p0, Wvb, vcn, 0, kof);
#pragma unroll
    for (int ks = 0; ks < 8; ++ks)
      acc = __builtin_amdgcn_mfma_f32_16x16x32_bf16(av[8 + ks], p1[ks], acc, 0, 0, 0);

    float bb = bvb[vc];
#pragma unroll
    for (int r = 0; r < 4; ++r) {
      float lg = acc[r] + bb;
      tg[r] += (vc == lbl[r]) ? lg : 0.f;
      float nm = fmaxf(mx[r], lg);
      sm[r] = sm[r] * __expf(mx[r] - nm) + __expf(lg - nm);
      mx[r] = nm;
    }
  }

#pragma unroll
  for (int off = 1; off <= 8; off <<= 1) {
#pragma unroll
    for (int r = 0; r < 4; ++r) {
      float om = __shfl_xor(mx[r], off, 64);
      float os = __shfl_xor(sm[r], off, 64);
      float ot = __shfl_xor(tg[r], off, 64);
      float nm = fmaxf(mx[r], om);
      sm[r] = sm[r] * __expf(mx[r] - nm) + os * __expf(om - nm);
      mx[r] = nm;
      tg[r] += ot;
    }
  }
  if (ln == 0) {
    int idx = (t * 2 + half) * 64 + m0 + ((l >> 4) << 2);
#pragma unroll
    for (int r = 0; r < 4; ++r) {
      pmx[idx + r] = mx[r]; psm[idx + r] = sm[r]; ptg[idx + r] = tg[r];
    }
  }
}

// ---------------- merge halves, per-row loss, sum ----------------
__global__ __launch_bounds__(256) void cemerge_k(const float* __restrict__ pmx,
                                                 const float* __restrict__ psm,
                                                 const float* __restrict__ ptg,
                                                 float* __restrict__ accum) {
  int g = blockIdx.x * 256 + threadIdx.x;   // 0..8191
  int t = g >> 6, row = g & 63;
  int i0 = (t * 2) * 64 + row, i1 = (t * 2 + 1) * 64 + row;
  float m0 = pmx[i0], m1 = pmx[i1];
  float M = fmaxf(m0, m1);
  float S = psm[i0] * __expf(m0 - M) + psm[i1] * __expf(m1 - M);
  float loss = M + logf(S) - (ptg[i0] + ptg[i1]);
#pragma unroll
  for (int off = 32; off >= 1; off >>= 1)
    loss += __shfl_xor(loss, off, 64);
  if ((threadIdx.x & 63) == 0) atomicAdd(accum, loss);
}

__global__ void finish_k(const float* __restrict__ accum, float* __restrict__ out) {
  out[0] = accum[0] * (1.f / (float)NROW);
}

// ---------------- launcher ----------------
extern "C" void kernel_launch(void* const* d_in, const int* in_sizes, int n_in,
                              void* d_out, int out_size, void* d_ws, size_t ws_size,
                              hipStream_t stream) {
  const int*   ids  = (const int*)  d_in[0];
  const int*   tgts = (const int*)  d_in[1];
  const float* emb  = (const float*)d_in[2];
  const float* W1   = (const float*)d_in[3];
  const float* b1   = (const float*)d_in[4];
  const float* W2   = (const float*)d_in[5];
  const float* b2   = (const float*)d_in[6];
  const float* Wv   = (const float*)d_in[7];
  const float* bv   = (const float*)d_in[8];
  float* out = (float*)d_out;

  // ws layout (bytes). REGION_A is time-shared: xb (pre-recur) -> h1all
  // (recur) -> Wvb (CE).
  char* ws = (char*)d_ws;
  unsigned short* G1    = (unsigned short*)(ws);                 // 33,554,432
  unsigned short* outsb = (unsigned short*)(ws + 33554432);      //  8,388,608 (=h2all)
  unsigned short* regA  = (unsigned short*)(ws + 41943040);      //  8,388,608
  unsigned short* xb    = regA;
  unsigned short* h1all = regA;
  unsigned short* Wvb   = regA;
  unsigned short* W1b   = (unsigned short*)(ws + 50331648);      //  2,097,152
  unsigned short* hzero = (unsigned short*)(ws + 52428800);      //     65,536
  float*          accum = (float*)         (ws + 52494336);      //          4
  float*          pmx   = (float*)         (ws + 52494400);      //     65,536
  float*          psm   = (float*)         (ws + 52559936);      //     65,536
  float*          ptg   = (float*)         (ws + 52625472);      //     65,536

  // zeros: hzero (16384 u32) + accum (1 u32, adjacent region start)
  fill_k<<<65, 256, 0, stream>>>((unsigned*)hzero, 0u, 16385);

  xgather_k<<<2048, 256, 0, stream>>>(ids, emb, xb);
  trans_k<<<256, 256, 0, stream>>>(W1, W1b, NG, 32);          // W1[0:512,:] -> W1b
  gemm1mm_k<<<256, 256, 0, stream>>>(xb, W1b, b1, G1);        // xb dead after this

  // sentinel-fill h1all (reuses xb region) and h2all
  fill_k<<<8192, 256, 0, stream>>>((unsigned*)h1all, SENT, 2097152);
  fill_k<<<8192, 256, 0, stream>>>((unsigned*)outsb, SENT, 2097152);

  {
    void* args[] = { (void*)&W1, (void*)&W2, (void*)&b2, (void*)&G1,
                     (void*)&hzero, (void*)&h1all, (void*)&outsb };
    hipError_t e = hipLaunchCooperativeKernel((const void*)recur_k,
                                              dim3(RBLK), dim3(RTH),
                                              args, 0, stream);
    if (e != hipSuccess) {
      // plain launch: 64 blocks on 256 CUs -> co-resident
      recur_k<<<dim3(RBLK), dim3(RTH), 0, stream>>>(W1, W2, b2, G1, hzero,
                                                    h1all, outsb);
    }
  }

  trans_k<<<1000, 256, 0, stream>>>(Wv, Wvb, V_SIZE, 125);    // Wv -> Wvb (h1all dead)

  ce_mfma_k<<<256, 256, 0, stream>>>(outsb, Wvb, bv, tgts, pmx, psm, ptg);
  cemerge_k<<<32, 256, 0, stream>>>(pmx, psm, ptg, accum);
  finish_k<<<1, 1, 0, stream>>>(accum, out);
}